// Round 12
// baseline (149.966 us; speedup 1.0000x reference)
//
#include <hip/hip_runtime.h>

#define I_DIM 17
#define H_DIM 128
#define T_DIM 19
#define B_DIM 32768
#define M_ROWS 128
#define NTHR 512
#define GRID (B_DIM / M_ROWS) /* 256 = one block per CU, ONE pass */
#define XI 323                /* T*I */
#define NF (M_ROWS * XI)      /* 41344 floats per block */
#define XSLOT 4352            /* per-t x slot: 8 rowgrp x 512B (k0..15) + 256B k16 plane */

#define OFF_H 0               /* 2 x 32768 */
#define OFF_X 65536           /* 19 x 4352 = 82688 */
#define OFF_WO 148224         /* 8 frags x 1024 = 8192 */
#define LDS_TOT 156416

typedef __bf16 bf16x8 __attribute__((ext_vector_type(8)));
typedef float f32x4 __attribute__((ext_vector_type(4)));
typedef float f32x4u __attribute__((ext_vector_type(4), aligned(4)));
union FragU { bf16x8 v; unsigned short s[8]; uint4 u; };

#define K1 1.4426950408889634f
#define K2 2.8853900817779268f

__device__ __forceinline__ unsigned short f2bf(float f) {
    union { float f; unsigned u; } x; x.f = f;
    return (unsigned short)((x.u + 0x8000u) >> 16);
}

/* T19: force fine MFMA/VALU/DS interleave for the step's scheduling region.
   Per wave per step: ~168 MFMA, ~580 VALU (incl 224 trans), ~52 ds_reads.
   Pattern {2 DS_READ, 5 MFMA, 18 VALU} x32; unsatisfiable groups are skipped. */
#define SGB_STEP() do {                                        \
    _Pragma("unroll")                                          \
    for (int it_ = 0; it_ < 32; ++it_) {                       \
        __builtin_amdgcn_sched_group_barrier(0x100, 2, 0);     \
        __builtin_amdgcn_sched_group_barrier(0x008, 5, 0);     \
        __builtin_amdgcn_sched_group_barrier(0x002, 18, 0);    \
    }                                                          \
} while (0)

/* TRANSPOSED gates MFMA for one quarter (rows (QT*2..QT*2+1)*16) into ACC_.
   D layout: reg r = gate-col cg*16+4q+r, lane l15 = batch-row. */
#define MFMA_Q(P_, QT_, ACC_, REC_) do {                                          \
    _Pragma("unroll") for (int m2 = 0; m2 < 2; ++m2) {                            \
        _Pragma("unroll") for (int g = 0; g < 4; ++g)                             \
            ACC_[m2][g] = bias[g];                                                \
        FragU fx; fx.u = (uint4){0u, 0u, 0u, 0u};                                 \
        if (q < 2)                                                                \
            fx.v = *(const bf16x8*)(smem + xyA + ((QT_) * 2 + m2) * 512);         \
        else if (q == 2)                                                          \
            fx.s[0] = *(const unsigned short*)(smem + xk16 + ((QT_) * 2 + m2) * 32); \
        _Pragma("unroll") for (int g = 0; g < 4; ++g)                             \
            ACC_[m2][g] = __builtin_amdgcn_mfma_f32_16x16x32_bf16(wihr[g], fx.v, ACC_[m2][g], 0, 0, 0); \
    }                                                                             \
    if (REC_) {                                                                   \
        _Pragma("unroll") for (int kk = 0; kk < 4; ++kk)                          \
            _Pragma("unroll") for (int m2 = 0; m2 < 2; ++m2) {                    \
                bf16x8 a = *(const bf16x8*)(smem + vkk[kk] + ((1 - (P_)) * 32768 + ((QT_) * 2 + m2) * 4096)); \
                _Pragma("unroll") for (int g = 0; g < 4; ++g)                     \
                    ACC_[m2][g] = __builtin_amdgcn_mfma_f32_16x16x32_bf16(whh[kk][g], a, ACC_[m2][g], 0, 0, 0); \
            }                                                                     \
    }                                                                             \
} while (0)

/* elementwise + packed b64 h-write for one quarter */
#define ELEM_Q(P_, QT_, ACC_) do {                                                \
    _Pragma("unroll") for (int m2 = 0; m2 < 2; ++m2) {                            \
        unsigned long long hp = 0ull;                                             \
        _Pragma("unroll") for (int r = 0; r < 4; ++r) {                           \
            float ui = __builtin_amdgcn_exp2f(ACC_[m2][0][r]);                    \
            float uf = __builtin_amdgcn_exp2f(ACC_[m2][1][r]);                    \
            float vg = __builtin_amdgcn_exp2f(ACC_[m2][2][r]);                    \
            float uo = __builtin_amdgcn_exp2f(ACC_[m2][3][r]);                    \
            float A_ = 1.f + ui, F_ = 1.f + uf, G_ = 1.f + vg;                    \
            float AG = A_ * G_;                                                   \
            int ci = (QT_) * 8 + m2 * 4 + r;                                      \
            float c = (cst[ci] * AG + (1.f - vg) * F_) * __builtin_amdgcn_rcpf(F_ * AG); \
            cst[ci] = c;                                                          \
            float vc = __builtin_amdgcn_exp2f(-K2 * c);                           \
            float h = (1.f - vc) * __builtin_amdgcn_rcpf((1.f + uo) * (1.f + vc));\
            union { float f; unsigned u; } hu; hu.f = h;                          \
            hp |= (unsigned long long)((hu.u + 0x8000u) >> 16) << (16 * r);       \
        }                                                                         \
        *(unsigned long long*)(smem + vwrT + ((P_) * 32768 + ((QT_) * 2 + m2) * 4096)) = hp; \
    }                                                                             \
} while (0)

/* y_{t-1}^T from H[1-P]: wave covers out-col tile yct, row-tiles rt0, rt0+1 */
#define Y_BURST(P_) do {                                                          \
    f32x4 ya0 = {0.f, 0.f, 0.f, 0.f}, ya1 = {0.f, 0.f, 0.f, 0.f};                 \
    _Pragma("unroll") for (int kk = 0; kk < 4; ++kk) {                            \
        bf16x8 wa = *(const bf16x8*)(smem + vwo + kk * 1024);                     \
        bf16x8 h0 = *(const bf16x8*)(smem + vkk[kk] + yrt + (1 - (P_)) * 32768);  \
        bf16x8 h1 = *(const bf16x8*)(smem + vkk[kk] + yrt + 4096 + (1 - (P_)) * 32768); \
        ya0 = __builtin_amdgcn_mfma_f32_16x16x32_bf16(wa, h0, ya0, 0, 0, 0);      \
        ya1 = __builtin_amdgcn_mfma_f32_16x16x32_bf16(wa, h1, ya1, 0, 0, 0);      \
    }                                                                             \
    if (yct == 0) {                                                               \
        *(f32x4u*)ypt0 = ya0 + ybo;                                               \
        *(f32x4u*)ypt1 = ya1 + ybo;                                               \
    } else if (q == 0) {                                                          \
        ypt0[0] = ya0[0] + ybo[0];                                                \
        ypt1[0] = ya1[0] + ybo[0];                                                \
    }                                                                             \
    ypt0 += I_DIM; ypt1 += I_DIM;                                                 \
} while (0)

/* full step, quarter ping-pong pipeline; P_ = t&1; writes H[P_], reads H[1-P_] */
#define STEP(P_) do {                      \
    MFMA_Q(P_, 0, accA, 1);                \
    MFMA_Q(P_, 1, accB, 1);                \
    ELEM_Q(P_, 0, accA);                   \
    MFMA_Q(P_, 2, accA, 1);                \
    ELEM_Q(P_, 1, accB);                   \
    MFMA_Q(P_, 3, accB, 1);                \
    ELEM_Q(P_, 2, accA);                   \
    Y_BURST(P_);                           \
    ELEM_Q(P_, 3, accB);                   \
    xyA += XSLOT; xk16 += XSLOT;           \
    SGB_STEP();                            \
    __syncthreads();                       \
} while (0)

__global__ __launch_bounds__(NTHR)
__attribute__((amdgpu_waves_per_eu(2, 2)))
void flowlstm(
    const float* __restrict__ x, const float* __restrict__ W_ih,
    const float* __restrict__ W_hh, const float* __restrict__ b_ih,
    const float* __restrict__ b_hh, const float* __restrict__ W_out,
    const float* __restrict__ b_out, float* __restrict__ out)
{
    __shared__ __align__(16) unsigned char smem[LDS_TOT];
    const int tid = threadIdx.x;
    const int w = tid >> 6, lane = tid & 63, l15 = lane & 15, q = lane >> 4;
    const int cg = w;                      /* wave owns gate-cols g*128 + cg*16 + (4q+r) */
    const int b0 = blockIdx.x * M_ROWS;

    /* ---- bulk x stage: coalesced dwords -> bf16 frag slots (k<16) + k16 plane ---- */
    {
        const float* xb = x + (size_t)b0 * XI;
        for (int j = 0; j < 81; ++j) {
            int f = tid + j * NTHR;
            if (f < NF) {
                float v = xb[f];
                unsigned uf_ = (unsigned)f;
                unsigned row = (uf_ * 51943u) >> 24;      /* f / 323 */
                unsigned s = uf_ - row * 323u;
                unsigned t = (s * 61681u) >> 20;          /* s / 17 */
                unsigned k = s - t * 17u;
                unsigned a;
                if (k == 16) a = OFF_X + t * XSLOT + 4096 + row * 2;
                else a = OFF_X + t * XSLOT + (row >> 4) * 512 + (k >> 3) * 256
                       + (row & 15) * 16 + (k & 7) * 2;
                *(unsigned short*)(smem + a) = f2bf(v);
            }
        }
    }
    /* ---- W_out fragments -> LDS (8 frags = ct*4+kk, N pad 17->32) ---- */
    {
        int ln = tid & 63, f = tid >> 6;
        int kk = f & 3, ct = f >> 2;
        int o = ct * 16 + (ln & 15);
        int kb = kk * 32 + (ln >> 4) * 8;
        FragU fu;
        #pragma unroll
        for (int e = 0; e < 8; ++e)
            fu.s[e] = (o < I_DIM) ? f2bf(W_out[o * H_DIM + kb + e]) : (unsigned short)0;
        *(uint4*)(smem + OFF_WO + f * 1024 + ln * 16) = fu.u;
    }
    /* gate scale: i,f,o -> -K1 ; g -> -K2 */
    float gsc[4] = { -K1, -K1, -K2, -K1 };

    /* ---- W_hh fragments in registers, PRE-SCALED (used as A-operand) ---- */
    bf16x8 whh[4][4];
    #pragma unroll
    for (int kk = 0; kk < 4; ++kk)
        #pragma unroll
        for (int g = 0; g < 4; ++g) {
            int n = g * H_DIM + cg * 16 + l15;
            const float* s = W_hh + n * H_DIM + kk * 32 + q * 8;
            FragU fu;
            #pragma unroll
            for (int e = 0; e < 8; ++e) fu.s[e] = f2bf(s[e] * gsc[g]);
            whh[kk][g] = fu.v;
        }
    /* ---- W_ih fragments in registers, PRE-SCALED (A-operand, K pad 17->32) ---- */
    bf16x8 wihr[4];
    #pragma unroll
    for (int g = 0; g < 4; ++g) {
        int n = g * H_DIM + cg * 16 + l15;
        FragU fu;
        #pragma unroll
        for (int e = 0; e < 8; ++e) {
            int k = q * 8 + e;
            fu.s[e] = (k < I_DIM) ? f2bf(W_ih[n * I_DIM + k] * gsc[g]) : (unsigned short)0;
        }
        wihr[g] = fu.v;
    }
    /* bias per (g, reg r): col = g*128 + cg*16 + 4q + r */
    f32x4 bias[4];
    #pragma unroll
    for (int g = 0; g < 4; ++g)
        #pragma unroll
        for (int r = 0; r < 4; ++r) {
            int col = g * H_DIM + cg * 16 + 4 * q + r;
            bias[g][r] = (b_ih[col] + b_hh[col]) * gsc[g];
        }
    /* ---- t-invariant LDS vaddrs ---- */
    const unsigned xr7 = (unsigned)((l15 & 7) << 4);
    unsigned vkk[4];
    #pragma unroll
    for (int kk = 0; kk < 4; ++kk)
        vkk[kk] = (unsigned)(l15 * 256 + ((kk * 64 + q * 16) ^ xr7));
    /* h-write: row = tile*16 + l15, cols cg*16+4q..+3 (b64); swizzle dep only on l15 */
    const unsigned vwrT = (unsigned)(l15 * 256 + (((cg * 16 + 4 * q) * 2) ^ xr7));
    /* y: out-col tile yct, row-tiles rt = (w>>1)*2, +1 */
    const int yct = w & 1;
    const unsigned yrt = (unsigned)((w >> 1) * 8192);
    const unsigned vwo = (unsigned)(OFF_WO + yct * 4096 + lane * 16);
    f32x4 ybo;
    #pragma unroll
    for (int r = 0; r < 4; ++r) {
        int col = yct * 16 + 4 * q + r;
        ybo[r] = b_out[col < I_DIM ? col : 16];
    }
    unsigned xyA  = (unsigned)(OFF_X + (q < 2 ? q * 256 : 0) + l15 * 16);
    unsigned xk16 = (unsigned)(OFF_X + 4096 + l15 * 2);
    float* ypt0 = out + (size_t)(b0 + (w >> 1) * 32 + l15) * XI + (yct ? 16 : 4 * q);
    float* ypt1 = ypt0 + (size_t)16 * XI;

    float cst[32];
    #pragma unroll
    for (int i = 0; i < 32; ++i) cst[i] = 0.f;

    f32x4 accA[2][4], accB[2][4];

    __syncthreads();   /* prologue staging visible */

    /* ---- peeled t=0: no recurrent GEMM, no y; writes H[0] ---- */
    MFMA_Q(0, 0, accA, 0);
    MFMA_Q(0, 1, accB, 0);
    ELEM_Q(0, 0, accA);
    MFMA_Q(0, 2, accA, 0);
    ELEM_Q(0, 1, accB);
    MFMA_Q(0, 3, accB, 0);
    ELEM_Q(0, 2, accA);
    ELEM_Q(0, 3, accB);
    xyA += XSLOT; xk16 += XSLOT;
    __syncthreads();

    /* ---- t = 1..18 ---- */
    #pragma unroll 1
    for (int t = 1; t < T_DIM; t += 2) {
        STEP(1);
        STEP(0);
    }

    /* ---- epilogue: y_18 from H[0] ---- */
    {
        f32x4 ya0 = {0.f, 0.f, 0.f, 0.f}, ya1 = {0.f, 0.f, 0.f, 0.f};
        #pragma unroll
        for (int kk = 0; kk < 4; ++kk) {
            bf16x8 wa = *(const bf16x8*)(smem + vwo + kk * 1024);
            bf16x8 h0 = *(const bf16x8*)(smem + vkk[kk] + yrt);
            bf16x8 h1 = *(const bf16x8*)(smem + vkk[kk] + yrt + 4096);
            ya0 = __builtin_amdgcn_mfma_f32_16x16x32_bf16(wa, h0, ya0, 0, 0, 0);
            ya1 = __builtin_amdgcn_mfma_f32_16x16x32_bf16(wa, h1, ya1, 0, 0, 0);
        }
        if (yct == 0) {
            *(f32x4u*)ypt0 = ya0 + ybo;
            *(f32x4u*)ypt1 = ya1 + ybo;
        } else if (q == 0) {
            ypt0[0] = ya0[0] + ybo[0];
            ypt1[0] = ya1[0] + ybo[0];
        }
    }
}

extern "C" void kernel_launch(void* const* d_in, const int* in_sizes, int n_in,
                              void* d_out, int out_size, void* d_ws, size_t ws_size,
                              hipStream_t stream) {
    const float* x     = (const float*)d_in[0];
    const float* W_ih  = (const float*)d_in[1];
    const float* W_hh  = (const float*)d_in[2];
    const float* b_ih  = (const float*)d_in[3];
    const float* b_hh  = (const float*)d_in[4];
    const float* W_out = (const float*)d_in[5];
    const float* b_out = (const float*)d_in[6];
    float* out = (float*)d_out;

    dim3 grid(GRID), block(NTHR);
    flowlstm<<<grid, block, 0, stream>>>(x, W_ih, W_hh, b_ih, b_hh, W_out, b_out, out);
}